// Round 1
// baseline (143943.286 us; speedup 1.0000x reference)
//
#include <hip/hip_runtime.h>

typedef __attribute__((ext_vector_type(4))) float f32x4;
typedef __attribute__((ext_vector_type(8))) short short8;
typedef __attribute__((ext_vector_type(4))) unsigned int u32x4;
typedef __attribute__((ext_vector_type(2))) unsigned int u32x2;

#define T_LEN 4096
#define HID 1024

__device__ __forceinline__ float bf2f(unsigned short u) {
  return __uint_as_float(((unsigned int)u) << 16);
}
__device__ __forceinline__ unsigned short f2bf(float f) {
  unsigned int x = __float_as_uint(f);
  unsigned int r = (x + 0x7fffu + ((x >> 16) & 1u)) >> 16;
  return (unsigned short)r;
}
__device__ __forceinline__ unsigned int pk2(float a, float b) {
  return (unsigned int)f2bf(a) | ((unsigned int)f2bf(b) << 16);
}
__device__ __forceinline__ float sigm(float x) { return 1.f / (1.f + __expf(-x)); }
__device__ __forceinline__ float tanh_f(float x) { return 2.f / (1.f + __expf(-2.f * x)) - 1.f; }

// ---------------- init: zero sync counters + convert x -> bf16 ----------------
__global__ void init_conv(const float* __restrict__ x, unsigned short* __restrict__ xbf,
                          unsigned int* __restrict__ cnt) {
  int gid = blockIdx.x * 256 + threadIdx.x;
  if (gid < 256) cnt[gid] = 0;
  const int n4 = (T_LEN * 2048) / 4;
  for (int i = gid; i < n4; i += gridDim.x * 256) {
    f32x4 v = *(const f32x4*)(x + (size_t)i * 4);
    u32x2 u;
    u[0] = pk2(v[0], v[1]);
    u[1] = pk2(v[2], v[3]);
    *(u32x2*)(xbf + (size_t)i * 4) = u;
  }
}

// ---------------- pre = seq @ w_ih.T + b_ih + b_hh  (bf16 MFMA GEMM) ----------------
// A: [T][2048] bf16 (seq). W: [2][4096][2048] fp32 (this layer). out: [2][T][4096] bf16
__global__ __launch_bounds__(256) void gemm_pre(
    const unsigned short* __restrict__ A, const float* __restrict__ W,
    const float* __restrict__ bih, const float* __restrict__ bhh,
    unsigned short* __restrict__ pre) {
  __shared__ unsigned short As[128][88];
  __shared__ unsigned short Bs[128][88];
  const int d = blockIdx.z;
  const int bn0 = blockIdx.x * 128;
  const int bm0 = blockIdx.y * 128;
  const float* Wd = W + (size_t)d * 4096 * 2048;
  const float* bi = bih + d * 4096;
  const float* bh = bhh + d * 4096;
  unsigned short* out = pre + (size_t)d * T_LEN * 4096;

  const int tid = threadIdx.x;
  const int lane = tid & 63;
  const int wid = tid >> 6;
  const int wr = wid >> 1, wc = wid & 1;
  const int fr = lane & 15, fq = lane >> 4;
  const int srow = tid >> 1;
  const int shalf = (tid & 1) * 32;

  f32x4 acc[4][4];
#pragma unroll
  for (int m = 0; m < 4; ++m)
#pragma unroll
    for (int n = 0; n < 4; ++n) acc[m][n] = 0.f;

  for (int k0 = 0; k0 < 2048; k0 += 64) {
    // stage A tile (already bf16): plain copy
    {
      const unsigned short* pA = A + (size_t)(bm0 + srow) * 2048 + k0 + shalf;
#pragma unroll
      for (int q = 0; q < 4; ++q) {
        u32x4 v = *(const u32x4*)(pA + q * 8);
        *(u32x4*)&As[srow][shalf + q * 8] = v;
      }
    }
    // stage B tile (fp32 -> bf16)
    {
      const float* pB = Wd + (size_t)(bn0 + srow) * 2048 + k0 + shalf;
#pragma unroll
      for (int q = 0; q < 4; ++q) {
        f32x4 x0 = *(const f32x4*)(pB + q * 8);
        f32x4 x1 = *(const f32x4*)(pB + q * 8 + 4);
        u32x4 u;
        u[0] = pk2(x0[0], x0[1]);
        u[1] = pk2(x0[2], x0[3]);
        u[2] = pk2(x1[0], x1[1]);
        u[3] = pk2(x1[2], x1[3]);
        *(u32x4*)&Bs[srow][shalf + q * 8] = u;
      }
    }
    __syncthreads();
#pragma unroll
    for (int ks = 0; ks < 64; ks += 32) {
      short8 af[4], bfr[4];
#pragma unroll
      for (int m = 0; m < 4; ++m)
        af[m] = *(const short8*)&As[wr * 64 + m * 16 + fr][ks + fq * 8];
#pragma unroll
      for (int n = 0; n < 4; ++n)
        bfr[n] = *(const short8*)&Bs[wc * 64 + n * 16 + fr][ks + fq * 8];
#pragma unroll
      for (int m = 0; m < 4; ++m)
#pragma unroll
        for (int n = 0; n < 4; ++n)
          acc[m][n] = __builtin_amdgcn_mfma_f32_16x16x32_bf16(af[m], bfr[n], acc[m][n], 0, 0, 0);
    }
    __syncthreads();
  }
#pragma unroll
  for (int m = 0; m < 4; ++m) {
#pragma unroll
    for (int n = 0; n < 4; ++n) {
      int col = bn0 + wc * 64 + n * 16 + fr;
      float bias = bi[col] + bh[col];
#pragma unroll
      for (int r = 0; r < 4; ++r) {
        int row = bm0 + wr * 64 + m * 16 + fq * 4 + r;
        out[(size_t)row * 4096 + col] = f2bf(acc[m][n][r] + bias);
      }
    }
  }
}

// ---------------- persistent bidirectional LSTM scan (one layer) ----------------
// 256 WGs x 256 thr. WG 0..127: fwd, 128..255: bwd. Each WG owns 8 hidden units;
// W_hh rows for its 4 gates x 8 units live in registers (fp32). Per step: stage h
// (agent-scope) into swizzled LDS, GEMV, 32-lane butterfly, leaders do gates +
// state update, then per-direction counter barrier.
__global__ __launch_bounds__(256, 1) void lstm_scan(
    const unsigned short* __restrict__ pre,  // [2][T][4096] bf16
    const float* __restrict__ whh,           // [2][4096][1024] fp32 (this layer)
    unsigned short* __restrict__ seqout,     // [T][2048] bf16
    float* __restrict__ hbuf,                // [2][2][1024] fp32
    unsigned int* __restrict__ cnt,          // 2 slots, 64B apart
    float* __restrict__ dout, int layer) {
  const int d = blockIdx.x >> 7;
  const int wg = blockIdx.x & 127;
  const int tid = threadIdx.x;
  const int ul = tid >> 5;   // unit_local 0..7
  const int cg = tid & 31;   // column group 0..31 (32 cols each)
  const int u = wg * 8 + ul; // global hidden unit
  const unsigned short* preD = pre + (size_t)d * T_LEN * 4096;
  const float* W = whh + (size_t)d * 4096 * 1024;
  float* hb = hbuf + d * 2048;
  unsigned int* c0 = cnt + d * 16;
  __shared__ float hs[1024];

  // Weights pre-permuted to match the LDS swizzle: wreg[g][p] pairs with
  // physical LDS slot p (logical col-block = p ^ (cg&7)). All indices static.
  f32x4 wreg[4][8];
#pragma unroll
  for (int g = 0; g < 4; ++g)
#pragma unroll
    for (int p = 0; p < 8; ++p) {
      const int colblk = p ^ (cg & 7);
      wreg[g][p] = *(const f32x4*)&W[(size_t)(g * 1024 + u) * 1024 + cg * 32 + colblk * 4];
    }

  const bool leader = (cg == 0);
  const int base = tid * 4;
  const int swz = ((tid >> 3) & 7) << 2;
  float cstate = 0.f;

  for (int s = 0; s < T_LEN; ++s) {
    const int t = d ? (T_LEN - 1 - s) : s;
    float pi = 0.f, pf = 0.f, pg = 0.f, po = 0.f;
    if (leader) {  // prefetch pre-activations early (independent of h)
      const unsigned short* pr = preD + (size_t)t * 4096;
      pi = bf2f(pr[u]);
      pf = bf2f(pr[1024 + u]);
      pg = bf2f(pr[2048 + u]);
      po = bf2f(pr[3072 + u]);
    }
    float a0 = 0.f, a1 = 0.f, a2 = 0.f, a3 = 0.f;
    if (s > 0) {
      const float* src = hb + (s & 1) * 1024;
      f32x4 hv;
#pragma unroll
      for (int k = 0; k < 4; ++k)
        hv[k] = __hip_atomic_load(src + base + k, __ATOMIC_RELAXED, __HIP_MEMORY_SCOPE_AGENT);
      *(f32x4*)&hs[base ^ swz] = hv;
      __syncthreads();
#pragma unroll
      for (int p = 0; p < 8; ++p) {
        f32x4 h4 = *(const f32x4*)&hs[cg * 32 + p * 4];
#pragma unroll
        for (int k = 0; k < 4; ++k) {
          a0 += wreg[0][p][k] * h4[k];
          a1 += wreg[1][p][k] * h4[k];
          a2 += wreg[2][p][k] * h4[k];
          a3 += wreg[3][p][k] * h4[k];
        }
      }
    }
#pragma unroll
    for (int m = 16; m >= 1; m >>= 1) {
      a0 += __shfl_xor(a0, m, 64);
      a1 += __shfl_xor(a1, m, 64);
      a2 += __shfl_xor(a2, m, 64);
      a3 += __shfl_xor(a3, m, 64);
    }
    if (leader) {
      float iG = sigm(a0 + pi);
      float fG = sigm(a1 + pf);
      float gG = tanh_f(a2 + pg);
      float oG = sigm(a3 + po);
      cstate = fG * cstate + iG * gG;
      float h = oG * tanh_f(cstate);
      seqout[(size_t)t * 2048 + d * 1024 + u] = f2bf(h);
      __hip_atomic_store(hb + ((s + 1) & 1) * 1024 + u, h, __ATOMIC_RELAXED,
                         __HIP_MEMORY_SCOPE_AGENT);
      if (s == T_LEN - 1) {
        dout[4096 + (2 * layer + d) * 1024 + u] = h;
        dout[4096 + 6144 + (2 * layer + d) * 1024 + u] = cstate;
      }
    }
    __syncthreads();  // drains leaders' stores (vmcnt 0 before barrier)
    if (tid == 0) {
      __hip_atomic_fetch_add(c0, 1u, __ATOMIC_RELEASE, __HIP_MEMORY_SCOPE_AGENT);
      const unsigned int target = (unsigned int)(s + 1) * 128u;
      while (__hip_atomic_load(c0, __ATOMIC_ACQUIRE, __HIP_MEMORY_SCOPE_AGENT) < target)
        __builtin_amdgcn_s_sleep(2);
    }
    __syncthreads();
  }
}

// ---------------- final FC: sig_out[t] = sigmoid(h_bwd3[t] . fc_w[7] + fc_b[7]) ----------------
__global__ void fc_out(const unsigned short* __restrict__ seq, const float* __restrict__ fcw,
                       const float* __restrict__ fcb, float* __restrict__ out) {
  const int lane = threadIdx.x & 63;
  const int wid = threadIdx.x >> 6;
  const int t = blockIdx.x * 4 + wid;
  if (t >= T_LEN) return;
  const unsigned short* h = seq + (size_t)t * 2048 + 1024;
  const float* w = fcw + 7 * 1024;
  const int j0 = lane * 16;
  float s = 0.f;
#pragma unroll
  for (int q = 0; q < 2; ++q) {
    u32x4 v = *(const u32x4*)(h + j0 + q * 8);
#pragma unroll
    for (int e = 0; e < 4; ++e) {
      float lo = bf2f((unsigned short)(v[e] & 0xffffu));
      float hi = bf2f((unsigned short)(v[e] >> 16));
      s += lo * w[j0 + q * 8 + e * 2] + hi * w[j0 + q * 8 + e * 2 + 1];
    }
  }
#pragma unroll
  for (int m = 32; m >= 1; m >>= 1) s += __shfl_xor(s, m, 64);
  if (lane == 0) out[t] = sigm(s + fcb[7]);
}

extern "C" void kernel_launch(void* const* d_in, const int* in_sizes, int n_in,
                              void* d_out, int out_size, void* d_ws, size_t ws_size,
                              hipStream_t stream) {
  (void)in_sizes; (void)n_in; (void)out_size; (void)ws_size;
  const float* x = (const float*)d_in[0];
  const float* wih = (const float*)d_in[3];
  const float* whh = (const float*)d_in[4];
  const float* bih = (const float*)d_in[5];
  const float* bhh = (const float*)d_in[6];
  const float* fcw = (const float*)d_in[7];
  const float* fcb = (const float*)d_in[8];
  float* out = (float*)d_out;
  char* ws = (char*)d_ws;

  unsigned int* cnt = (unsigned int*)ws;                       // 4 KB counters
  float* hbuf = (float*)(ws + 4096);                           // 16 KB h broadcast
  unsigned short* xbf = (unsigned short*)(ws + 65536);         // 16 MB
  unsigned short* seqA = (unsigned short*)(ws + 65536 + 16777216);      // 16 MB
  unsigned short* seqB = (unsigned short*)(ws + 65536 + 2 * 16777216);  // 16 MB
  unsigned short* pre = (unsigned short*)(ws + 65536 + 3 * 16777216);   // 64 MB

  init_conv<<<2048, 256, 0, stream>>>(x, xbf, cnt);

  const unsigned short* sin_[3] = {xbf, seqA, seqB};
  unsigned short* sout_[3] = {seqA, seqB, seqA};
  for (int l = 0; l < 3; ++l) {
    gemm_pre<<<dim3(32, 32, 2), 256, 0, stream>>>(
        sin_[l], wih + (size_t)l * 2 * 4096 * 2048, bih + l * 8192, bhh + l * 8192, pre);
    const unsigned short* preArg = pre;
    const float* whhArg = whh + (size_t)l * 2 * 4096 * 1024;
    unsigned short* soArg = sout_[l];
    float* hbArg = hbuf;
    unsigned int* cntArg = cnt + l * 32;
    float* doutArg = out;
    int layerArg = l;
    void* args[7];
    args[0] = &preArg;
    args[1] = &whhArg;
    args[2] = &soArg;
    args[3] = &hbArg;
    args[4] = &cntArg;
    args[5] = &doutArg;
    args[6] = &layerArg;
    hipLaunchCooperativeKernel((void*)lstm_scan, dim3(256), dim3(256), args, 0, stream);
  }
  fc_out<<<1024, 256, 0, stream>>>(seqA, fcw, fcb, out);
}

// Round 2
// 25509.006 us; speedup vs baseline: 5.6428x; 5.6428x over previous
//
#include <hip/hip_runtime.h>

typedef __attribute__((ext_vector_type(4))) float f32x4;
typedef __attribute__((ext_vector_type(8))) short short8;
typedef __attribute__((ext_vector_type(4))) unsigned int u32x4;
typedef __attribute__((ext_vector_type(2))) unsigned int u32x2;

#define T_LEN 4096
#define SENT 0x7FC0DEADu

__device__ __forceinline__ float bf2f(unsigned short u) {
  return __uint_as_float(((unsigned int)u) << 16);
}
__device__ __forceinline__ unsigned short f2bf(float f) {
  unsigned int x = __float_as_uint(f);
  unsigned int r = (x + 0x7fffu + ((x >> 16) & 1u)) >> 16;
  return (unsigned short)r;
}
__device__ __forceinline__ unsigned int pk2(float a, float b) {
  return (unsigned int)f2bf(a) | ((unsigned int)f2bf(b) << 16);
}
__device__ __forceinline__ float sigm(float x) { return 1.f / (1.f + __expf(-x)); }
__device__ __forceinline__ float tanh_f(float x) { return 2.f / (1.f + __expf(-2.f * x)) - 1.f; }

// ---------------- convert x -> bf16 ----------------
__global__ void init_conv(const float* __restrict__ x, unsigned short* __restrict__ xbf) {
  int gid = blockIdx.x * 256 + threadIdx.x;
  const int n4 = (T_LEN * 2048) / 4;
  for (int i = gid; i < n4; i += gridDim.x * 256) {
    f32x4 v = *(const f32x4*)(x + (size_t)i * 4);
    u32x2 u;
    u[0] = pk2(v[0], v[1]);
    u[1] = pk2(v[2], v[3]);
    *(u32x2*)(xbf + (size_t)i * 4) = u;
  }
}

// ---------------- per-layer prep: poison hbuf sentinel + convert W_hh -> bf16 ----------------
// grid 4096 x 256 = 1,048,576 threads. hbuf: 8M floats (8/thread). whh layer: 8M floats (2 f32x4/thread).
__global__ void prep_layer(const float* __restrict__ whh_l, unsigned short* __restrict__ whhb,
                           float* __restrict__ hbuf) {
  const int gid = blockIdx.x * 256 + threadIdx.x;
  {
    u32x4 s4;
    s4[0] = s4[1] = s4[2] = s4[3] = SENT;
    unsigned int* hb = (unsigned int*)hbuf;
    *(u32x4*)(hb + (size_t)gid * 8) = s4;
    *(u32x4*)(hb + (size_t)gid * 8 + 4) = s4;
  }
#pragma unroll
  for (int r = 0; r < 2; ++r) {
    const size_t i = (size_t)gid * 2 + r;
    f32x4 v = *(const f32x4*)(whh_l + i * 4);
    u32x2 u2;
    u2[0] = pk2(v[0], v[1]);
    u2[1] = pk2(v[2], v[3]);
    *(u32x2*)(whhb + i * 4) = u2;
  }
}

// ---------------- pre = seq @ w_ih.T + b_ih + b_hh  (bf16 MFMA GEMM) ----------------
__global__ __launch_bounds__(256) void gemm_pre(
    const unsigned short* __restrict__ A, const float* __restrict__ W,
    const float* __restrict__ bih, const float* __restrict__ bhh,
    unsigned short* __restrict__ pre) {
  __shared__ unsigned short As[128][88];
  __shared__ unsigned short Bs[128][88];
  const int d = blockIdx.z;
  const int bn0 = blockIdx.x * 128;
  const int bm0 = blockIdx.y * 128;
  const float* Wd = W + (size_t)d * 4096 * 2048;
  const float* bi = bih + d * 4096;
  const float* bh = bhh + d * 4096;
  unsigned short* out = pre + (size_t)d * T_LEN * 4096;

  const int tid = threadIdx.x;
  const int lane = tid & 63;
  const int wid = tid >> 6;
  const int wr = wid >> 1, wc = wid & 1;
  const int fr = lane & 15, fq = lane >> 4;
  const int srow = tid >> 1;
  const int shalf = (tid & 1) * 32;

  f32x4 acc[4][4];
#pragma unroll
  for (int m = 0; m < 4; ++m)
#pragma unroll
    for (int n = 0; n < 4; ++n) acc[m][n] = 0.f;

  for (int k0 = 0; k0 < 2048; k0 += 64) {
    {
      const unsigned short* pA = A + (size_t)(bm0 + srow) * 2048 + k0 + shalf;
#pragma unroll
      for (int q = 0; q < 4; ++q) {
        u32x4 v = *(const u32x4*)(pA + q * 8);
        *(u32x4*)&As[srow][shalf + q * 8] = v;
      }
    }
    {
      const float* pB = Wd + (size_t)(bn0 + srow) * 2048 + k0 + shalf;
#pragma unroll
      for (int q = 0; q < 4; ++q) {
        f32x4 x0 = *(const f32x4*)(pB + q * 8);
        f32x4 x1 = *(const f32x4*)(pB + q * 8 + 4);
        u32x4 u;
        u[0] = pk2(x0[0], x0[1]);
        u[1] = pk2(x0[2], x0[3]);
        u[2] = pk2(x1[0], x1[1]);
        u[3] = pk2(x1[2], x1[3]);
        *(u32x4*)&Bs[srow][shalf + q * 8] = u;
      }
    }
    __syncthreads();
#pragma unroll
    for (int ks = 0; ks < 64; ks += 32) {
      short8 af[4], bfr[4];
#pragma unroll
      for (int m = 0; m < 4; ++m)
        af[m] = *(const short8*)&As[wr * 64 + m * 16 + fr][ks + fq * 8];
#pragma unroll
      for (int n = 0; n < 4; ++n)
        bfr[n] = *(const short8*)&Bs[wc * 64 + n * 16 + fr][ks + fq * 8];
#pragma unroll
      for (int m = 0; m < 4; ++m)
#pragma unroll
        for (int n = 0; n < 4; ++n)
          acc[m][n] = __builtin_amdgcn_mfma_f32_16x16x32_bf16(af[m], bfr[n], acc[m][n], 0, 0, 0);
    }
    __syncthreads();
  }
#pragma unroll
  for (int m = 0; m < 4; ++m) {
#pragma unroll
    for (int n = 0; n < 4; ++n) {
      int col = bn0 + wc * 64 + n * 16 + fr;
      float bias = bi[col] + bh[col];
#pragma unroll
      for (int r = 0; r < 4; ++r) {
        int row = bm0 + wr * 64 + m * 16 + fq * 4 + r;
        out[(size_t)row * 4096 + col] = f2bf(acc[m][n][r] + bias);
      }
    }
  }
}

// ---------------- persistent bidirectional LSTM scan (one layer) ----------------
// 256 WGs x 256 thr. WG 0..127: fwd, 128..255: bwd. Each WG owns 8 hidden units.
// Sync = data-as-flag: hbuf[d][s][1024] poisoned to SENT; producers (leaders) store
// h via relaxed agent-scope dword stores; consumers poll-load exactly their 4 floats
// until no element is SENT. No barriers, no atomic RMW.
__global__ __launch_bounds__(256, 1) void lstm_scan(
    const unsigned short* __restrict__ pre,   // [2][T][4096] bf16
    const unsigned short* __restrict__ whhb,  // [2][4096][1024] bf16 (this layer)
    unsigned short* __restrict__ seqout,      // [T][2048] bf16
    float* __restrict__ hbuf,                 // [2][T][1024] fp32 sentinel-sync
    float* __restrict__ dout, int layer) {
  const int d = blockIdx.x >> 7;
  const int wg = blockIdx.x & 127;
  const int tid = threadIdx.x;
  const int ul = tid >> 5;   // unit_local 0..7
  const int cg = tid & 31;   // column group 0..31 (32 cols each)
  const int u = wg * 8 + ul;
  const unsigned short* preD = pre + (size_t)d * T_LEN * 4096;
  const unsigned short* W = whhb + (size_t)d * 4096 * 1024;
  float* hb = hbuf + (size_t)d * T_LEN * 1024;
  __shared__ float hs[32 * 33];  // +1-padded rows: bank = (cg + j) mod 32, conflict-free

  // Per-thread W_hh slice: unit u, 4 gates, cols [cg*32, cg*32+32) as packed bf16.
  u32x4 wq[4][4];
#pragma unroll
  for (int g = 0; g < 4; ++g)
#pragma unroll
    for (int q = 0; q < 4; ++q)
      wq[g][q] = *(const u32x4*)&W[(size_t)(g * 1024 + u) * 1024 + cg * 32 + q * 8];
  // Pin in VGPRs: opaque to the compiler -> no rematerialization/reload per step.
#pragma unroll
  for (int g = 0; g < 4; ++g)
#pragma unroll
    for (int q = 0; q < 4; ++q) asm volatile("" : "+v"(wq[g][q]));

  const bool leader = (cg == 0);
  const int wrow = tid >> 3;
  const int wcol = (tid & 7) << 2;
  float cstate = 0.f;

  for (int s = 0; s < T_LEN; ++s) {
    const int t = d ? (T_LEN - 1 - s) : s;
    float pi = 0.f, pf = 0.f, pg = 0.f, po = 0.f;
    if (leader) {  // issue early: hides L2/HBM latency under the poll wait
      const unsigned short* pr = preD + (size_t)t * 4096;
      pi = bf2f(pr[u]);
      pf = bf2f(pr[1024 + u]);
      pg = bf2f(pr[2048 + u]);
      po = bf2f(pr[3072 + u]);
    }
    float a[4] = {0.f, 0.f, 0.f, 0.f};
    if (s > 0) {
      const float* src = hb + (size_t)(s - 1) * 1024 + tid * 4;
      float h0, h1, h2, h3;
      for (;;) {
        h0 = __hip_atomic_load(src + 0, __ATOMIC_RELAXED, __HIP_MEMORY_SCOPE_AGENT);
        h1 = __hip_atomic_load(src + 1, __ATOMIC_RELAXED, __HIP_MEMORY_SCOPE_AGENT);
        h2 = __hip_atomic_load(src + 2, __ATOMIC_RELAXED, __HIP_MEMORY_SCOPE_AGENT);
        h3 = __hip_atomic_load(src + 3, __ATOMIC_RELAXED, __HIP_MEMORY_SCOPE_AGENT);
        if (__float_as_uint(h0) != SENT && __float_as_uint(h1) != SENT &&
            __float_as_uint(h2) != SENT && __float_as_uint(h3) != SENT)
          break;
        __builtin_amdgcn_s_sleep(1);
      }
      __syncthreads();  // previous step's GEMV reads of hs are done
      hs[wrow * 33 + wcol + 0] = h0;
      hs[wrow * 33 + wcol + 1] = h1;
      hs[wrow * 33 + wcol + 2] = h2;
      hs[wrow * 33 + wcol + 3] = h3;
      __syncthreads();  // hs ready
#pragma unroll
      for (int q = 0; q < 4; ++q) {
        float hh[8];
#pragma unroll
        for (int e = 0; e < 8; ++e) hh[e] = hs[cg * 33 + q * 8 + e];
#pragma unroll
        for (int g = 0; g < 4; ++g) {
          u32x4 w4 = wq[g][q];
#pragma unroll
          for (int e = 0; e < 4; ++e) {
            float wl = __uint_as_float(w4[e] << 16);
            float wh = __uint_as_float(w4[e] & 0xffff0000u);
            a[g] += wl * hh[2 * e] + wh * hh[2 * e + 1];
          }
        }
      }
    }
#pragma unroll
    for (int g = 0; g < 4; ++g)
#pragma unroll
      for (int m = 16; m >= 1; m >>= 1) a[g] += __shfl_xor(a[g], m, 64);
    if (leader) {
      float iG = sigm(a[0] + pi);
      float fG = sigm(a[1] + pf);
      float gG = tanh_f(a[2] + pg);
      float oG = sigm(a[3] + po);
      cstate = fG * cstate + iG * gG;
      float h = oG * tanh_f(cstate);
      // critical-path store first: agent-scope relaxed dword -> visible at L3
      __hip_atomic_store(hb + (size_t)s * 1024 + u, h, __ATOMIC_RELAXED,
                         __HIP_MEMORY_SCOPE_AGENT);
      seqout[(size_t)t * 2048 + d * 1024 + u] = f2bf(h);
      if (s == T_LEN - 1) {
        dout[4096 + (2 * layer + d) * 1024 + u] = h;
        dout[4096 + 6144 + (2 * layer + d) * 1024 + u] = cstate;
      }
    }
  }
}

// ---------------- final FC: sig_out[t] = sigmoid(h_bwd3[t] . fc_w[7] + fc_b[7]) ----------------
__global__ void fc_out(const unsigned short* __restrict__ seq, const float* __restrict__ fcw,
                       const float* __restrict__ fcb, float* __restrict__ out) {
  const int lane = threadIdx.x & 63;
  const int wid = threadIdx.x >> 6;
  const int t = blockIdx.x * 4 + wid;
  if (t >= T_LEN) return;
  const unsigned short* h = seq + (size_t)t * 2048 + 1024;
  const float* w = fcw + 7 * 1024;
  const int j0 = lane * 16;
  float s = 0.f;
#pragma unroll
  for (int q = 0; q < 2; ++q) {
    u32x4 v = *(const u32x4*)(h + j0 + q * 8);
#pragma unroll
    for (int e = 0; e < 4; ++e) {
      float lo = bf2f((unsigned short)(v[e] & 0xffffu));
      float hi = bf2f((unsigned short)(v[e] >> 16));
      s += lo * w[j0 + q * 8 + e * 2] + hi * w[j0 + q * 8 + e * 2 + 1];
    }
  }
#pragma unroll
  for (int m = 32; m >= 1; m >>= 1) s += __shfl_xor(s, m, 64);
  if (lane == 0) out[t] = sigm(s + fcb[7]);
}

extern "C" void kernel_launch(void* const* d_in, const int* in_sizes, int n_in,
                              void* d_out, int out_size, void* d_ws, size_t ws_size,
                              hipStream_t stream) {
  (void)in_sizes; (void)n_in; (void)out_size; (void)ws_size;
  const float* x = (const float*)d_in[0];
  const float* wih = (const float*)d_in[3];
  const float* whh = (const float*)d_in[4];
  const float* bih = (const float*)d_in[5];
  const float* bhh = (const float*)d_in[6];
  const float* fcw = (const float*)d_in[7];
  const float* fcb = (const float*)d_in[8];
  float* out = (float*)d_out;
  char* ws = (char*)d_ws;

  float* hbuf = (float*)(ws + 65536);                                   // 32 MB
  unsigned short* xbf = (unsigned short*)(ws + 65536 + (size_t)32 * 1048576);   // 16 MB
  unsigned short* seqA = (unsigned short*)(ws + 65536 + (size_t)48 * 1048576);  // 16 MB
  unsigned short* pre = (unsigned short*)(ws + 65536 + (size_t)64 * 1048576);   // 64 MB
  unsigned short* whhb = (unsigned short*)(ws + 65536 + (size_t)128 * 1048576); // 16 MB

  init_conv<<<2048, 256, 0, stream>>>(x, xbf);

  const unsigned short* sin_[3] = {xbf, seqA, xbf};
  unsigned short* sout_[3] = {seqA, xbf, seqA};
  for (int l = 0; l < 3; ++l) {
    gemm_pre<<<dim3(32, 32, 2), 256, 0, stream>>>(
        sin_[l], wih + (size_t)l * 2 * 4096 * 2048, bih + l * 8192, bhh + l * 8192, pre);
    prep_layer<<<4096, 256, 0, stream>>>(whh + (size_t)l * 2 * 4096 * 1024, whhb, hbuf);

    const unsigned short* preArg = pre;
    const unsigned short* whhArg = whhb;
    unsigned short* soArg = sout_[l];
    float* hbArg = hbuf;
    float* doutArg = out;
    int layerArg = l;
    void* args[6];
    args[0] = &preArg;
    args[1] = &whhArg;
    args[2] = &soArg;
    args[3] = &hbArg;
    args[4] = &doutArg;
    args[5] = &layerArg;
    hipLaunchCooperativeKernel((void*)lstm_scan, dim3(256), dim3(256), args, 0, stream);
  }
  fc_out<<<1024, 256, 0, stream>>>(seqA, fcw, fcb, out);
}

// Round 3
// 22148.277 us; speedup vs baseline: 6.4991x; 1.1517x over previous
//
#include <hip/hip_runtime.h>

typedef __attribute__((ext_vector_type(4))) float f32x4;
typedef __attribute__((ext_vector_type(8))) short short8;
typedef __attribute__((ext_vector_type(4))) unsigned int u32x4;
typedef __attribute__((ext_vector_type(2))) unsigned int u32x2;

#define T_LEN 4096
#define SENTP 0x7FC07FC0u  // bf16 NaN pair — h is always finite

__device__ __forceinline__ float bf2f(unsigned short u) {
  return __uint_as_float(((unsigned int)u) << 16);
}
__device__ __forceinline__ unsigned short f2bf(float f) {
  unsigned int x = __float_as_uint(f);
  unsigned int r = (x + 0x7fffu + ((x >> 16) & 1u)) >> 16;
  return (unsigned short)r;
}
__device__ __forceinline__ unsigned int pk2(float a, float b) {
  return (unsigned int)f2bf(a) | ((unsigned int)f2bf(b) << 16);
}
__device__ __forceinline__ float sigm(float x) { return 1.f / (1.f + __expf(-x)); }
__device__ __forceinline__ float tanh_f(float x) { return 2.f / (1.f + __expf(-2.f * x)) - 1.f; }

#if __has_builtin(__builtin_amdgcn_fdot2_f32_bf16)
typedef __attribute__((ext_vector_type(2))) short bf16x2;
__device__ __forceinline__ float dot2bf(unsigned int w, unsigned int h, float c) {
  bf16x2 a, b;
  __builtin_memcpy(&a, &w, 4);
  __builtin_memcpy(&b, &h, 4);
  return __builtin_amdgcn_fdot2_f32_bf16(a, b, c, false);
}
#else
__device__ __forceinline__ float dot2bf(unsigned int w, unsigned int h, float c) {
  float wl = __uint_as_float(w << 16), wh = __uint_as_float(w & 0xffff0000u);
  float hl = __uint_as_float(h << 16), hh = __uint_as_float(h & 0xffff0000u);
  return c + wl * hl + wh * hh;
}
#endif

// ---------------- convert x -> bf16 ----------------
__global__ void init_conv(const float* __restrict__ x, unsigned short* __restrict__ xbf) {
  int gid = blockIdx.x * 256 + threadIdx.x;
  const int n4 = (T_LEN * 2048) / 4;
  for (int i = gid; i < n4; i += gridDim.x * 256) {
    f32x4 v = *(const f32x4*)(x + (size_t)i * 4);
    u32x2 u;
    u[0] = pk2(v[0], v[1]);
    u[1] = pk2(v[2], v[3]);
    *(u32x2*)(xbf + (size_t)i * 4) = u;
  }
}

// ---------------- per-layer prep: poison hbuf (bf16-pair sentinel) + convert W_hh -> bf16 ----------------
// grid 4096 x 256 = 1,048,576 threads. hbuf: 4M dwords (4/thread). whh layer: 8M floats (2 f32x4/thread).
__global__ void prep_layer(const float* __restrict__ whh_l, unsigned short* __restrict__ whhb,
                           unsigned int* __restrict__ hbuf) {
  const int gid = blockIdx.x * 256 + threadIdx.x;
  {
    u32x4 s4;
    s4[0] = s4[1] = s4[2] = s4[3] = SENTP;
    *(u32x4*)(hbuf + (size_t)gid * 4) = s4;
  }
#pragma unroll
  for (int r = 0; r < 2; ++r) {
    const size_t i = (size_t)gid * 2 + r;
    f32x4 v = *(const f32x4*)(whh_l + i * 4);
    u32x2 u2;
    u2[0] = pk2(v[0], v[1]);
    u2[1] = pk2(v[2], v[3]);
    *(u32x2*)(whhb + i * 4) = u2;
  }
}

// ---------------- pre = seq @ w_ih.T + b_ih + b_hh  (bf16 MFMA GEMM) ----------------
__global__ __launch_bounds__(256) void gemm_pre(
    const unsigned short* __restrict__ A, const float* __restrict__ W,
    const float* __restrict__ bih, const float* __restrict__ bhh,
    unsigned short* __restrict__ pre) {
  __shared__ unsigned short As[128][88];
  __shared__ unsigned short Bs[128][88];
  const int d = blockIdx.z;
  const int bn0 = blockIdx.x * 128;
  const int bm0 = blockIdx.y * 128;
  const float* Wd = W + (size_t)d * 4096 * 2048;
  const float* bi = bih + d * 4096;
  const float* bh = bhh + d * 4096;
  unsigned short* out = pre + (size_t)d * T_LEN * 4096;

  const int tid = threadIdx.x;
  const int lane = tid & 63;
  const int wid = tid >> 6;
  const int wr = wid >> 1, wc = wid & 1;
  const int fr = lane & 15, fq = lane >> 4;
  const int srow = tid >> 1;
  const int shalf = (tid & 1) * 32;

  f32x4 acc[4][4];
#pragma unroll
  for (int m = 0; m < 4; ++m)
#pragma unroll
    for (int n = 0; n < 4; ++n) acc[m][n] = 0.f;

  for (int k0 = 0; k0 < 2048; k0 += 64) {
    {
      const unsigned short* pA = A + (size_t)(bm0 + srow) * 2048 + k0 + shalf;
#pragma unroll
      for (int q = 0; q < 4; ++q) {
        u32x4 v = *(const u32x4*)(pA + q * 8);
        *(u32x4*)&As[srow][shalf + q * 8] = v;
      }
    }
    {
      const float* pB = Wd + (size_t)(bn0 + srow) * 2048 + k0 + shalf;
#pragma unroll
      for (int q = 0; q < 4; ++q) {
        f32x4 x0 = *(const f32x4*)(pB + q * 8);
        f32x4 x1 = *(const f32x4*)(pB + q * 8 + 4);
        u32x4 u;
        u[0] = pk2(x0[0], x0[1]);
        u[1] = pk2(x0[2], x0[3]);
        u[2] = pk2(x1[0], x1[1]);
        u[3] = pk2(x1[2], x1[3]);
        *(u32x4*)&Bs[srow][shalf + q * 8] = u;
      }
    }
    __syncthreads();
#pragma unroll
    for (int ks = 0; ks < 64; ks += 32) {
      short8 af[4], bfr[4];
#pragma unroll
      for (int m = 0; m < 4; ++m)
        af[m] = *(const short8*)&As[wr * 64 + m * 16 + fr][ks + fq * 8];
#pragma unroll
      for (int n = 0; n < 4; ++n)
        bfr[n] = *(const short8*)&Bs[wc * 64 + n * 16 + fr][ks + fq * 8];
#pragma unroll
      for (int m = 0; m < 4; ++m)
#pragma unroll
        for (int n = 0; n < 4; ++n)
          acc[m][n] = __builtin_amdgcn_mfma_f32_16x16x32_bf16(af[m], bfr[n], acc[m][n], 0, 0, 0);
    }
    __syncthreads();
  }
#pragma unroll
  for (int m = 0; m < 4; ++m) {
#pragma unroll
    for (int n = 0; n < 4; ++n) {
      int col = bn0 + wc * 64 + n * 16 + fr;
      float bias = bi[col] + bh[col];
#pragma unroll
      for (int r = 0; r < 4; ++r) {
        int row = bm0 + wr * 64 + m * 16 + fq * 4 + r;
        out[(size_t)row * 4096 + col] = f2bf(acc[m][n][r] + bias);
      }
    }
  }
}

// ---------------- persistent bidirectional LSTM scan (one layer) ----------------
// 256 WGs x 256 thr. WG 0..127: fwd, 128..255: bwd. Each WG owns 8 hidden units.
// Dataflow sync: hbuf[d][s][512] u32 (bf16 h pairs) poisoned to NaN-pair sentinel;
// producers store packed dwords (agent relaxed), consumers poll ONE 8B atomic load.
__global__ __launch_bounds__(256, 1) void lstm_scan(
    const unsigned short* __restrict__ pre,   // [2][T][4096] bf16
    const unsigned short* __restrict__ whhb,  // [2][4096][1024] bf16 (this layer)
    unsigned short* __restrict__ seqout,      // [T][2048] bf16
    unsigned int* __restrict__ hbuf,          // [2][T][512] u32 bf16-pairs
    float* __restrict__ dout, int layer) {
  const int d = blockIdx.x >> 7;
  const int wg = blockIdx.x & 127;
  const int tid = threadIdx.x;
  const int ul = tid >> 5;   // unit_local 0..7
  const int cg = tid & 31;   // column group 0..31 (32 cols each)
  const int u = wg * 8 + ul;
  const unsigned short* preD = pre + (size_t)d * T_LEN * 4096;
  const unsigned short* W = whhb + (size_t)d * 4096 * 1024;
  unsigned int* hb = hbuf + (size_t)d * T_LEN * 512;
  // 18-dword padded rows; row r = h dwords [16r,16r+16) (h cols [32r,32r+32)).
  // b64 reads: lanes cg and cg+16 share a bank pair -> 2-way (free, m136).
  __shared__ unsigned int hs[2][32 * 18];

  // Per-thread W_hh slice: unit u, 4 gates, cols [cg*32, cg*32+32) packed bf16.
  u32x4 wq[4][4];
#pragma unroll
  for (int g = 0; g < 4; ++g)
#pragma unroll
    for (int q = 0; q < 4; ++q)
      wq[g][q] = *(const u32x4*)&W[(size_t)(g * 1024 + u) * 1024 + cg * 32 + q * 8];
#pragma unroll
  for (int g = 0; g < 4; ++g)
#pragma unroll
    for (int q = 0; q < 4; ++q) asm volatile("" : "+v"(wq[g][q]));  // pin in VGPRs

  const int wa = (tid >> 3) * 18 + (tid & 7) * 2;  // LDS write addr (dwords)
  float cstate = 0.f;

  for (int s = 0; s < T_LEN; ++s) {
    const int t = d ? (T_LEN - 1 - s) : s;
    float pi = 0.f, pf = 0.f, pg = 0.f, po = 0.f;
    if (cg == 0) {  // issue early: overlaps the poll wait
      const unsigned short* pr = preD + (size_t)t * 4096;
      pi = bf2f(pr[u]);
      pf = bf2f(pr[1024 + u]);
      pg = bf2f(pr[2048 + u]);
      po = bf2f(pr[3072 + u]);
    }
    float a[4] = {0.f, 0.f, 0.f, 0.f};
    if (s > 0) {
      const unsigned long long* src =
          (const unsigned long long*)(hb + (size_t)(s - 1) * 512) + tid;
      unsigned long long v;
      for (;;) {
        v = __hip_atomic_load(src, __ATOMIC_RELAXED, __HIP_MEMORY_SCOPE_AGENT);
        if ((unsigned int)v != SENTP && (unsigned int)(v >> 32) != SENTP) break;
        __builtin_amdgcn_s_sleep(1);
      }
      u32x2 wv;
      wv[0] = (unsigned int)v;
      wv[1] = (unsigned int)(v >> 32);
      *(u32x2*)&hs[s & 1][wa] = wv;
      __syncthreads();  // hs[s&1] ready (parity dbuf kills the WAR barrier)
      const unsigned int* hrow = &hs[s & 1][cg * 18];
#pragma unroll
      for (int q = 0; q < 4; ++q) {
        u32x2 hA = *(const u32x2*)&hrow[4 * q];
        u32x2 hB = *(const u32x2*)&hrow[4 * q + 2];
        unsigned int hd0 = hA[0], hd1 = hA[1], hd2 = hB[0], hd3 = hB[1];
#pragma unroll
        for (int g = 0; g < 4; ++g) {
          a[g] = dot2bf(wq[g][q][0], hd0, a[g]);
          a[g] = dot2bf(wq[g][q][1], hd1, a[g]);
          a[g] = dot2bf(wq[g][q][2], hd2, a[g]);
          a[g] = dot2bf(wq[g][q][3], hd3, a[g]);
        }
      }
    }
    // leaders seed pre BEFORE the butterfly: the sum (incl. pre) lands on all 32 lanes
    if (cg == 0) {
      a[0] += pi;
      a[1] += pf;
      a[2] += pg;
      a[3] += po;
    }
#pragma unroll
    for (int g = 0; g < 4; ++g)
#pragma unroll
      for (int m = 16; m >= 1; m >>= 1) a[g] += __shfl_xor(a[g], m, 64);
    // all lanes compute gates redundantly (identical inputs -> identical results)
    float iG = sigm(a[0]);
    float fG = sigm(a[1]);
    float gG = tanh_f(a[2]);
    float oG = sigm(a[3]);
    cstate = fG * cstate + iG * gG;
    float h = oG * tanh_f(cstate);
    float h_other = __shfl_xor(h, 32, 64);  // other unit of this wave
    if ((tid & 63) == 0) {                  // wave leader: units u (even), u+1
      unsigned int hp = pk2(h, h_other);
      __hip_atomic_store(hb + (size_t)s * 512 + wg * 4 + (tid >> 6), hp,
                         __ATOMIC_RELAXED, __HIP_MEMORY_SCOPE_AGENT);
      *(unsigned int*)&seqout[(size_t)t * 2048 + d * 1024 + u] = hp;
    }
    if (s == T_LEN - 1 && cg == 0) {
      dout[4096 + (2 * layer + d) * 1024 + u] = h;
      dout[4096 + 6144 + (2 * layer + d) * 1024 + u] = cstate;
    }
  }
}

// ---------------- final FC: sig_out[t] = sigmoid(h_bwd3[t] . fc_w[7] + fc_b[7]) ----------------
__global__ void fc_out(const unsigned short* __restrict__ seq, const float* __restrict__ fcw,
                       const float* __restrict__ fcb, float* __restrict__ out) {
  const int lane = threadIdx.x & 63;
  const int wid = threadIdx.x >> 6;
  const int t = blockIdx.x * 4 + wid;
  if (t >= T_LEN) return;
  const unsigned short* h = seq + (size_t)t * 2048 + 1024;
  const float* w = fcw + 7 * 1024;
  const int j0 = lane * 16;
  float s = 0.f;
#pragma unroll
  for (int q = 0; q < 2; ++q) {
    u32x4 v = *(const u32x4*)(h + j0 + q * 8);
#pragma unroll
    for (int e = 0; e < 4; ++e) {
      float lo = bf2f((unsigned short)(v[e] & 0xffffu));
      float hi = bf2f((unsigned short)(v[e] >> 16));
      s += lo * w[j0 + q * 8 + e * 2] + hi * w[j0 + q * 8 + e * 2 + 1];
    }
  }
#pragma unroll
  for (int m = 32; m >= 1; m >>= 1) s += __shfl_xor(s, m, 64);
  if (lane == 0) out[t] = sigm(s + fcb[7]);
}

extern "C" void kernel_launch(void* const* d_in, const int* in_sizes, int n_in,
                              void* d_out, int out_size, void* d_ws, size_t ws_size,
                              hipStream_t stream) {
  (void)in_sizes; (void)n_in; (void)out_size; (void)ws_size;
  const float* x = (const float*)d_in[0];
  const float* wih = (const float*)d_in[3];
  const float* whh = (const float*)d_in[4];
  const float* bih = (const float*)d_in[5];
  const float* bhh = (const float*)d_in[6];
  const float* fcw = (const float*)d_in[7];
  const float* fcb = (const float*)d_in[8];
  float* out = (float*)d_out;
  char* ws = (char*)d_ws;

  unsigned int* hbuf = (unsigned int*)(ws + 65536);                             // 16 MB
  unsigned short* xbf = (unsigned short*)(ws + 65536 + (size_t)32 * 1048576);   // 16 MB
  unsigned short* seqA = (unsigned short*)(ws + 65536 + (size_t)48 * 1048576);  // 16 MB
  unsigned short* pre = (unsigned short*)(ws + 65536 + (size_t)64 * 1048576);   // 64 MB
  unsigned short* whhb = (unsigned short*)(ws + 65536 + (size_t)128 * 1048576); // 16 MB

  init_conv<<<2048, 256, 0, stream>>>(x, xbf);

  const unsigned short* sin_[3] = {xbf, seqA, xbf};
  unsigned short* sout_[3] = {seqA, xbf, seqA};
  for (int l = 0; l < 3; ++l) {
    gemm_pre<<<dim3(32, 32, 2), 256, 0, stream>>>(
        sin_[l], wih + (size_t)l * 2 * 4096 * 2048, bih + l * 8192, bhh + l * 8192, pre);
    prep_layer<<<4096, 256, 0, stream>>>(whh + (size_t)l * 2 * 4096 * 1024, whhb, hbuf);

    const unsigned short* preArg = pre;
    const unsigned short* whhArg = whhb;
    unsigned short* soArg = sout_[l];
    unsigned int* hbArg = hbuf;
    float* doutArg = out;
    int layerArg = l;
    void* args[6];
    args[0] = &preArg;
    args[1] = &whhArg;
    args[2] = &soArg;
    args[3] = &hbArg;
    args[4] = &doutArg;
    args[5] = &layerArg;
    hipLaunchCooperativeKernel((void*)lstm_scan, dim3(256), dim3(256), args, 0, stream);
  }
  fc_out<<<1024, 256, 0, stream>>>(seqA, fcw, fcb, out);
}